// Round 18
// baseline (243.231 us; speedup 1.0000x reference)
//
#include <hip/hip_runtime.h>
#include <hip/hip_bf16.h>

// Problem constants: B=64, Cin=3, H=W=64, O=16, k=7, fh=fw=58
#define NBUCK 2048
#define WB 0.005859375f         // bucket width 12/2048, range [-6,6)
#define SCALE 170.6666667f      // 1/WB
#define PGRP 16                 // planes per block (4 quarters of 64)
#define VALID_PER_BLOCK 53824.f // 58*58*16

// output geometry
#define SEG 10092u              // fh*fh*Cin
#define OSEG 161472u            // O*SEG
#define OUT1 10334208u          // B*OSEG
#define NOUT 31002624u          // 3*OUT1

typedef float v4f __attribute__((ext_vector_type(4)));

// ---------------------------------------------------------------------------
// 0) zero: gsum banks (1 tiny block; R1 showed 1-block nodes cost ~0).
// ---------------------------------------------------------------------------
__global__ void zero_kernel(float* __restrict__ gsum)
{
    if (threadIdx.x < 64) gsum[threadIdx.x] = 0.f;
}

// ---------------------------------------------------------------------------
// 1) hist_query: 588 blocks = (c*49+t)*4 + quarter. FUSED build+query:
//    - histogram ONLY the tap's valid pixels of 16 planes into LDS
//      (validity exact -> no corner pack / row-col inclusion-exclusion)
//    - in-place C/D block scan -> T table in LDS
//    - 32 lerp queries from LDS, partial (A,L) atomics to gsum.
//    Linearity of T in counts and of lerp in T makes plane-partials exact.
//    (R15-R17 lesson: structure changes didn't move build/query; the cost
//    scales with serial node count & total issued work -> minimize both.)
// ---------------------------------------------------------------------------
__global__ __launch_bounds__(1024) void hist_query_kernel(
    const float* __restrict__ x,
    const float* __restrict__ Kh, const float* __restrict__ Km,
    float* __restrict__ gsum)
{
    __shared__ float sH[NBUCK + 1];     // counts -> T in place (+ T[2048])
    __shared__ float sWc[16], sWd[16];
    __shared__ float sS[1];

    const int blk = blockIdx.x;
    const int grp = blk & 3;            // plane quarter
    const int ct  = blk >> 2;           // c*49 + t
    const int c   = ct / 49;
    const int t   = ct - c * 49;
    const int dy  = t / 7, dx = t - dy * 7;
    const int tid = threadIdx.x;

    sH[tid] = 0.f; sH[tid + 1024] = 0.f;
    if (tid == 0) sH[NBUCK] = 0.f;
    __syncthreads();

    // 16 planes, one float4 per thread per plane (4096 px = 1024 float4)
    const int idx0 = tid * 4;
    const int py   = idx0 >> 6;         // row; same for all 4 elems
    const int px0  = idx0 & 63;
    const bool oky = ((unsigned)(py - dy)) < 58u;
    bool okx[4];
#pragma unroll
    for (int e = 0; e < 4; ++e)
        okx[e] = oky && (((unsigned)(px0 + e - dx)) < 58u);

    for (int p = 0; p < PGRP; ++p) {
        const int plane = (grp * PGRP + p) * 3 + c;
        float4 val = ((const float4*)x)[plane * 1024 + tid];
        float vv[4] = {val.x, val.y, val.z, val.w};
#pragma unroll
        for (int e = 0; e < 4; ++e) {
            if (okx[e]) {
                const int b = min(max((int)fmaf(vv[e], SCALE, 1024.f), 0), NBUCK - 1);
                atomicAdd(&sH[b], 1.f);
            }
        }
    }
    __syncthreads();

    // in-place block scan via C/D identity (2 buckets/thread):
    // T[b] = T0 + WB*(2*(b*C[b] - D[b]) - b*N), T0 = WB*(Dtot + 0.5*N)
    const int lane = tid & 63;
    const int wid  = tid >> 6;
    const int b0 = 2 * tid, b1 = 2 * tid + 1;
    const float c0 = sH[b0], c1 = sH[b1];
    const float d0 = (float)b0 * c0, d1 = (float)b1 * c1;
    const float cs = c0 + c1, ds = d0 + d1;

    float ic = cs, id = ds;
#pragma unroll
    for (int off = 1; off < 64; off <<= 1) {
        const float tc = __shfl_up(ic, off);
        const float td = __shfl_up(id, off);
        if (lane >= off) { ic += tc; id += td; }
    }
    if (lane == 63) { sWc[wid] = ic; sWd[wid] = id; }
    __syncthreads();

    float baseC = 0.f, baseD = 0.f, Ntot = 0.f, Dtot = 0.f;
#pragma unroll
    for (int w = 0; w < 16; ++w) {
        const float wc = sWc[w], wd = sWd[w];
        Ntot += wc; Dtot += wd;
        if (w < wid) { baseC += wc; baseD += wd; }
    }
    const float Cex = baseC + ic - cs;      // exclusive count prefix at b0
    const float Dex = baseD + id - ds;      // exclusive b*cnt prefix at b0
    const float T0  = WB * (Dtot + 0.5f * Ntot);
    __syncthreads();                        // all reads of sH counts done

    sH[b0] = T0 + WB * (2.f * ((float)b0 * Cex - Dex) - (float)b0 * Ntot);
    const float C1 = Cex + c0, D1 = Dex + d0;
    sH[b1] = T0 + WB * (2.f * ((float)b1 * C1 - D1) - (float)b1 * Ntot);
    if (tid == 1023) {
        sH[NBUCK] = T0 + WB * ((float)NBUCK * Ntot - 2.f * Dtot);
        sS[0] = T0 - 6.f * Ntot;            // sum of snapped valid values
    }
    __syncthreads();

    // 32 queries (hm*16+o) from LDS T
    if (tid < 32) {
        const int hm = tid >> 4, o = tid & 15;
        const float k = (hm ? Km : Kh)[o * 147 + c * 49 + t];
        const float u = fmaf(k, SCALE, 1024.f);
        const int j = min(max((int)u, 0), NBUCK - 1);
        const float fr = u - (float)j;
        const float A = sH[j] + fr * (sH[j + 1] - sH[j]);
        const float L = k * VALID_PER_BLOCK - sS[0];
        atomicAdd(&gsum[tid], A);           // A-bank
        atomicAdd(&gsum[32 + tid], L);      // L-bank
    }
}

// ---------------------------------------------------------------------------
// 2) fill: fold A/L banks -> s_hit/s_miss; broadcast-fill 124 MB (roofline).
//    s_hit = -0.5*(L_h + A_h);  s_miss = 0.5*(A_m - L_m)
// ---------------------------------------------------------------------------
__global__ __launch_bounds__(256) void fill_kernel(
    const float* __restrict__ gsum, v4f* __restrict__ out, unsigned n4)
{
    __shared__ float sv[48];
    if (threadIdx.x < 48) {
        const int o = threadIdx.x & 15, grp = threadIdx.x >> 4;
        const float h = -0.5f * (gsum[32 + o] + gsum[o]);
        const float m =  0.5f * (gsum[16 + o] - gsum[48 + o]);
        sv[threadIdx.x] = (grp == 0) ? (h - m) : ((grp == 1) ? h : m);
    }
    __syncthreads();
    const unsigned stride = gridDim.x * blockDim.x;
    for (unsigned i = blockIdx.x * blockDim.x + threadIdx.x; i < n4; i += stride) {
        const unsigned f = i * 4u;
        const unsigned w   = f / OUT1;
        const unsigned rem = f - w * OUT1;
        const unsigned o   = (rem % OSEG) / SEG;
        const float val = sv[w * 16 + o];
        v4f pk = {val, val, val, val};
        __builtin_nontemporal_store(pk, &out[i]);
    }
}

extern "C" void kernel_launch(void* const* d_in, const int* in_sizes, int n_in,
                              void* d_out, int out_size, void* d_ws, size_t ws_size,
                              hipStream_t stream)
{
    const float* x  = (const float*)d_in[0];
    const float* Kh = (const float*)d_in[1];
    const float* Km = (const float*)d_in[2];
    float* out  = (float*)d_out;
    float* gsum = (float*)d_ws;    // 64 floats: [0..32) A-bank, [32..64) L-bank

    zero_kernel      <<<1, 64, 0, stream>>>(gsum);
    hist_query_kernel<<<588, 1024, 0, stream>>>(x, Kh, Km, gsum);
    fill_kernel      <<<4096, 256, 0, stream>>>(gsum, (v4f*)out, NOUT / 4u);
}

// Round 19
// 103.756 us; speedup vs baseline: 2.3443x; 2.3443x over previous
//
#include <hip/hip_runtime.h>
#include <hip/hip_bf16.h>

// Problem constants: B=64, Cin=3, H=W=64, O=16, k=7, fh=fw=58
#define NBUCK 2048
#define WB 0.005859375f         // bucket width 12/2048, range [-6,6)
#define SCALE 170.6666667f      // 1/WB
#define NVALID 215296.f         // 58*58*64

// output geometry
#define SEG 10092u
#define OSEG 161472u
#define OUT1 10334208u
#define NOUT 31002624u

// scratch in the TAIL of d_out (fill overwrites last). float offsets:
#define TAIL_BASE (NOUT - 4194304u)    // 26,808,320
#define T_XT   0u                       // transposed x: [192][64][64] (px-major)
#define T_PART 786432u                  // [768][2048] F hist partials
#define T_MID  2359296u                 // [48][2048] mid partials
#define T_TTAB 2457600u                 // [3][2050] T tables
#define T_STOT 2463750u                 // [3] exact channel sums

typedef float v4f __attribute__((ext_vector_type(4)));

// ---------------------------------------------------------------------------
// 1) transpose: xT[plane][px][py] = x[plane][py][px]; blk0 zeros gsum+Stot.
// ---------------------------------------------------------------------------
__global__ __launch_bounds__(256) void transpose_kernel(
    const float* __restrict__ x, float* __restrict__ tail, float* __restrict__ gsum)
{
    __shared__ float sT[64][65];
    const int plane = blockIdx.x;
    const int tid = threadIdx.x;
    if (plane == 0) {
        if (tid < 64) gsum[tid] = 0.f;
        if (tid < 3)  tail[T_STOT + tid] = 0.f;
    }
    const float4* x4 = (const float4*)(x + plane * 4096);
    v4f* o4 = (v4f*)(tail + T_XT + (unsigned)plane * 4096u);
#pragma unroll
    for (int it = 0; it < 4; ++it) {
        const int i = it * 256 + tid;
        float4 v = x4[i];
        const int row = i >> 4, c4 = (i & 15) * 4;
        sT[row][c4] = v.x; sT[row][c4+1] = v.y; sT[row][c4+2] = v.z; sT[row][c4+3] = v.w;
    }
    __syncthreads();
#pragma unroll
    for (int it = 0; it < 4; ++it) {
        const int i = it * 256 + tid;
        const int px = i >> 4, py0 = (i & 15) * 4;
        v4f w = {sT[py0][px], sT[py0+1][px], sT[py0+2][px], sT[py0+3][px]};
        o4[i] = w;
    }
}

// ---------------------------------------------------------------------------
// 2) hist: 768 blocks (c*256 + batch*4 + qtr), 256 thr, 1024 px each.
//    ~1K LDS atomics/block (R18 measured 4.2 cyc/atomic -> ~2us wall).
//    Also accumulates exact Stot[c]. Partial hist -> private slot.
// ---------------------------------------------------------------------------
__global__ __launch_bounds__(256) void hist_kernel(
    const float* __restrict__ x, float* __restrict__ tail)
{
    __shared__ float sH[NBUCK];
    __shared__ float sSum[4];
    const int blk = blockIdx.x;
    const int c = blk >> 8, rem = blk & 255;
    const int batch = rem >> 2, qtr = rem & 3;
    const int plane = batch * 3 + c;
    const int tid = threadIdx.x;
    for (int i = tid; i < NBUCK; i += 256) sH[i] = 0.f;
    __syncthreads();

    float4 v = ((const float4*)x)[plane * 1024 + qtr * 256 + tid];
    float vv[4] = {v.x, v.y, v.z, v.w};
#pragma unroll
    for (int e = 0; e < 4; ++e) {
        const int b = min(max((int)fmaf(vv[e], SCALE, 1024.f), 0), NBUCK - 1);
        atomicAdd(&sH[b], 1.f);
    }
    // exact channel sum
    float s = vv[0] + vv[1] + vv[2] + vv[3];
    const int lane = tid & 63, wv = tid >> 6;
#pragma unroll
    for (int off = 32; off > 0; off >>= 1) s += __shfl_down(s, off);
    if (lane == 0) sSum[wv] = s;
    __syncthreads();
    if (tid == 0)
        atomicAdd(&tail[T_STOT + c], sSum[0] + sSum[1] + sSum[2] + sSum[3]);
    float* dst = tail + T_PART + (unsigned)blk * 2048u;
    for (int i = tid; i < NBUCK; i += 256) dst[i] = sH[i];
}

// ---------------------------------------------------------------------------
// 3) reduceA: 48 blocks (c*16+g) x 256 thr: mid = sum of 16 partials.
// ---------------------------------------------------------------------------
__global__ __launch_bounds__(256) void reduceA_kernel(float* __restrict__ tail)
{
    const int cg = blockIdx.x;          // c*16 + g
    const int tid = threadIdx.x;
#pragma unroll
    for (int bo = 0; bo < 8; ++bo) {
        const int b = bo * 256 + tid;
        float s = 0.f;
#pragma unroll
        for (int i = 0; i < 16; ++i)
            s += tail[T_PART + (unsigned)(cg * 16 + i) * 2048u + b];
        tail[T_MID + (unsigned)cg * 2048u + b] = s;
    }
}

// ---------------------------------------------------------------------------
// 4) scanB: 3 blocks x 1024 thr: sum 16 mids, C/D block scan -> T[2049].
//    (scan formula verbatim from R18 -- numerically validated there.)
// ---------------------------------------------------------------------------
__global__ __launch_bounds__(1024) void scanB_kernel(float* __restrict__ tail)
{
    __shared__ float sWc[16], sWd[16];
    const int c = blockIdx.x;
    const int tid = threadIdx.x;
    const int b0 = 2 * tid, b1 = 2 * tid + 1;
    float c0 = 0.f, c1 = 0.f;
#pragma unroll
    for (int g = 0; g < 16; ++g) {
        c0 += tail[T_MID + (unsigned)(c * 16 + g) * 2048u + b0];
        c1 += tail[T_MID + (unsigned)(c * 16 + g) * 2048u + b1];
    }
    const float d0 = (float)b0 * c0, d1 = (float)b1 * c1;
    const float cs = c0 + c1, ds = d0 + d1;
    const int lane = tid & 63, wid = tid >> 6;
    float ic = cs, id = ds;
#pragma unroll
    for (int off = 1; off < 64; off <<= 1) {
        const float tc = __shfl_up(ic, off);
        const float td = __shfl_up(id, off);
        if (lane >= off) { ic += tc; id += td; }
    }
    if (lane == 63) { sWc[wid] = ic; sWd[wid] = id; }
    __syncthreads();
    float baseC = 0.f, baseD = 0.f, Ntot = 0.f, Dtot = 0.f;
#pragma unroll
    for (int w = 0; w < 16; ++w) {
        const float wc = sWc[w], wd = sWd[w];
        Ntot += wc; Dtot += wd;
        if (w < wid) { baseC += wc; baseD += wd; }
    }
    const float Cex = baseC + ic - cs;
    const float Dex = baseD + id - ds;
    const float T0 = WB * (Dtot + 0.5f * Ntot);
    float* T = tail + T_TTAB + (unsigned)c * 2050u;
    T[b0] = T0 + WB * (2.f * ((float)b0 * Cex - Dex) - (float)b0 * Ntot);
    const float C1 = Cex + c0, D1 = Dex + d0;
    T[b1] = T0 + WB * (2.f * ((float)b1 * C1 - D1) - (float)b1 * Ntot);
    if (tid == 1023)
        T[NBUCK] = T0 + WB * ((float)NBUCK * Ntot - 2.f * Dtot);
}

// ---------------------------------------------------------------------------
// 5) boundary: 588 blocks = (c*49+t)*4+bg, 1024 thr. EXACT invalid-region
//    eval in registers (dense VALU -- the idle pipe): stage 11712 invalid
//    values (rows from x coalesced, cols from xT coalesced) -> 12/thread ->
//    32-query unrolled |k-v| loop. bg0 also adds the F-table lerp + linear.
//    A(q,c,t) = lerpF(k) - sum|k-v|_inv ; L = k*215296 - Stot + sum v_inv.
// ---------------------------------------------------------------------------
__global__ __launch_bounds__(1024) void boundary_kernel(
    const float* __restrict__ x,
    const float* __restrict__ Kh, const float* __restrict__ Km,
    const float* __restrict__ tail, float* __restrict__ gsum)
{
    __shared__ float sV[12288];         // 48 KB (padded with zeros)
    __shared__ float sK[32];
    __shared__ float sred[16][33];

    const int blk = blockIdx.x;
    const int bg = blk & 3;
    const int ct = blk >> 2;
    const int c = ct / 49, t = ct - c * 49;
    const int dy = t / 7, dx = t - dy * 7;
    const int tid = threadIdx.x;

    // rows part: 6 invalid rows x 64 px x 16 planes = 6144 (f4 coalesced)
    if (tid < 1536) {
        const int p = tid / 96, rem = tid - p * 96;
        const int r = rem >> 4, c4 = rem & 15;
        const int rinv = (r < dy) ? r : 58 + r;
        const int plane = (bg * 16 + p) * 3 + c;
        float4 v = ((const float4*)x)[plane * 1024 + rinv * 16 + c4];
        v4f w = {v.x, v.y, v.z, v.w};
        ((v4f*)sV)[tid] = w;
    }
    // cols part: 6 invalid cols x 58 valid rows x 16 planes = 5568 (from xT)
    for (int s = tid; s < 5568; s += 1024) {
        const int p = s / 348, rem = s - p * 348;
        const int i = rem / 58, j = rem - i * 58;
        const int ci = (i < dx) ? i : 58 + i;
        const int plane = (bg * 16 + p) * 3 + c;
        sV[6144 + s] = tail[T_XT + (unsigned)plane * 4096u + ci * 64 + dy + j];
    }
    if (tid < 576) sV[11712 + tid] = 0.f;             // pad (threads >=976 idle)
    if (tid < 32)
        sK[tid] = ((tid >= 16) ? Km : Kh)[(tid & 15) * 147 + c * 49 + t];
    __syncthreads();

    float acc[32];
#pragma unroll
    for (int q = 0; q < 32; ++q) acc[q] = 0.f;
    float svs = 0.f;

    if (tid < 976) {                                   // 976*12 == 11712 exactly
        float v[12];
        const v4f* sv4 = (const v4f*)sV;
#pragma unroll
        for (int g = 0; g < 3; ++g) {
            v4f w = sv4[tid * 3 + g];
            v[g * 4] = w.x; v[g * 4 + 1] = w.y; v[g * 4 + 2] = w.z; v[g * 4 + 3] = w.w;
        }
#pragma unroll
        for (int e = 0; e < 12; ++e) svs += v[e];
#pragma unroll
        for (int q = 0; q < 32; ++q) {
            const float k = sK[q];
            float a = 0.f;
#pragma unroll
            for (int e = 0; e < 12; ++e) a += fabsf(k - v[e]);
            acc[q] = a;
        }
    }

    // wave reduce 33 values -> LDS -> 64 atomics
    const int lane = tid & 63, wv = tid >> 6;
#pragma unroll
    for (int q = 0; q < 32; ++q) {
        float a = acc[q];
#pragma unroll
        for (int off = 32; off > 0; off >>= 1) a += __shfl_down(a, off);
        if (lane == 0) sred[wv][q] = a;
    }
#pragma unroll
    for (int off = 32; off > 0; off >>= 1) svs += __shfl_down(svs, off);
    if (lane == 0) sred[wv][32] = svs;
    __syncthreads();

    if (tid < 32) {
        float aq = 0.f, si = 0.f;
#pragma unroll
        for (int w = 0; w < 16; ++w) { aq += sred[w][tid]; si += sred[w][32]; }
        atomicAdd(&gsum[tid], -aq);                    // A-bank -= exact invalid
        atomicAdd(&gsum[32 + tid], si);                // L-bank += sum v_inv
        if (bg == 0) {                                 // F lerp + linear, once per (c,t)
            const float k = sK[tid];
            const float u = fmaf(k, SCALE, 1024.f);
            const int j = min(max((int)u, 0), NBUCK - 1);
            const float fr = u - (float)j;
            const float* T = tail + T_TTAB + (unsigned)c * 2050u;
            const float A = T[j] + fr * (T[j + 1] - T[j]);
            atomicAdd(&gsum[tid], A);
            atomicAdd(&gsum[32 + tid], fmaf(k, NVALID, -tail[T_STOT + c]));
        }
    }
}

// ---------------------------------------------------------------------------
// 6) fill: fold banks -> s_hit/s_miss; broadcast-fill 124 MB (roofline).
// ---------------------------------------------------------------------------
__global__ __launch_bounds__(256) void fill_kernel(
    const float* __restrict__ gsum, v4f* __restrict__ out, unsigned n4)
{
    __shared__ float sv[48];
    if (threadIdx.x < 48) {
        const int o = threadIdx.x & 15, grp = threadIdx.x >> 4;
        const float h = -0.5f * (gsum[32 + o] + gsum[o]);
        const float m =  0.5f * (gsum[16 + o] - gsum[48 + o]);
        sv[threadIdx.x] = (grp == 0) ? (h - m) : ((grp == 1) ? h : m);
    }
    __syncthreads();
    const unsigned stride = gridDim.x * blockDim.x;
    for (unsigned i = blockIdx.x * blockDim.x + threadIdx.x; i < n4; i += stride) {
        const unsigned f = i * 4u;
        const unsigned w   = f / OUT1;
        const unsigned rem = f - w * OUT1;
        const unsigned o   = (rem % OSEG) / SEG;
        const float val = sv[w * 16 + o];
        v4f pk = {val, val, val, val};
        __builtin_nontemporal_store(pk, &out[i]);
    }
}

extern "C" void kernel_launch(void* const* d_in, const int* in_sizes, int n_in,
                              void* d_out, int out_size, void* d_ws, size_t ws_size,
                              hipStream_t stream)
{
    const float* x  = (const float*)d_in[0];
    const float* Kh = (const float*)d_in[1];
    const float* Km = (const float*)d_in[2];
    float* out  = (float*)d_out;
    float* tail = out + TAIL_BASE;
    float* gsum = (float*)d_ws;    // 64 floats: [0..32) A-bank, [32..64) L-bank

    transpose_kernel<<<192, 256, 0, stream>>>(x, tail, gsum);
    hist_kernel     <<<768, 256, 0, stream>>>(x, tail);
    reduceA_kernel  <<<48, 256, 0, stream>>>(tail);
    scanB_kernel    <<<3, 1024, 0, stream>>>(tail);
    boundary_kernel <<<588, 1024, 0, stream>>>(x, Kh, Km, tail, gsum);
    fill_kernel     <<<4096, 256, 0, stream>>>(gsum, (v4f*)out, NOUT / 4u);
}

// Round 20
// 53.843 us; speedup vs baseline: 4.5174x; 1.9270x over previous
//
#include <hip/hip_runtime.h>
#include <hip/hip_bf16.h>

// Problem constants: B=64, Cin=3, H=W=64, O=16, k=7, fh=fw=58
#define NBUCK 2048
#define WB 0.005859375f         // bucket width 12/2048, range [-6,6)
#define SCALE 170.6666667f      // 1/WB

// output geometry
#define SEG 10092u
#define OSEG 161472u
#define OUT1 10334208u
#define NOUT 31002624u

// scratch in TAIL of d_out (fill overwrites last). float offsets:
// F partial tables TRANSPOSED: F_tr[bucket 0..2048][96 slots = c*32+g]
// row/col tables TRANSPOSED:  RC_tr[bucket][72 slots = c*24 + (ri | 12+ci)]
#define TAIL_BASE (NOUT - 524288u)     // 30,478,336 (16B aligned)
#define F_TR   0u                       // [2049][96]  = 196,704
#define RC_TR  196704u                  // [2049][72]  = 147,528
#define SF_OFF 344232u                  // [96]
#define SRC_OFF 344328u                 // [72]
#define PACK   344400u                  // [3][144][64] corner pixels

typedef float v4f __attribute__((ext_vector_type(4)));

// ---------------------------------------------------------------------------
// 1) build: 168 blocks x 1024. blk<96: F 2-plane partial (c=blk/32,g=blk%32,
//    8K LDS atomics -- halved vs R15's 16K critical path) + corner pack.
//    blk 96..131: full row tables (4K atomics). blk 132..167: full col tables.
//    Each block scans its hist in place (R15-verbatim C/D identity) and
//    writes T TRANSPOSED so query reads contiguous per-bucket rows.
// ---------------------------------------------------------------------------
__global__ __launch_bounds__(1024) void build_kernel(
    const float* __restrict__ x, float* __restrict__ tail, float* __restrict__ gsum)
{
    __shared__ float sH[NBUCK];
    __shared__ float sWc[16], sWd[16];
    const int blk = blockIdx.x;
    const int tid = threadIdx.x;
    sH[tid] = 0.f; sH[tid + 1024] = 0.f;
    if (blk == 0 && tid < 64) gsum[tid] = 0.f;
    __syncthreads();

    int slot, stride;
    unsigned baseT, baseS;
    if (blk < 96) {
        const int c = blk / 32, g = blk % 32;
        slot = c * 32 + g; stride = 96; baseT = F_TR; baseS = SF_OFF;
#pragma unroll
        for (int pb = 0; pb < 2; ++pb) {
            const int batch = 2 * g + pb;
            const int plane = batch * 3 + c;
            float4 val = ((const float4*)x)[plane * 1024 + tid];
            float vv[4] = {val.x, val.y, val.z, val.w};
            const int pix0 = tid * 4;
#pragma unroll
            for (int e = 0; e < 4; ++e) {
                const int idx = pix0 + e;
                const int py = idx >> 6, px = idx & 63;
                const float v = vv[e];
                const int b = min(max((int)fmaf(v, SCALE, 1024.f), 0), NBUCK - 1);
                atomicAdd(&sH[b], 1.f);
                const bool rb = (py < 6) | (py >= 58);
                const bool cb = (px < 6) | (px >= 58);
                if (rb & cb) {
                    const int ri = (py < 6) ? py : py - 52;
                    const int ci = (px < 6) ? px : px - 52;
                    tail[PACK + ((unsigned)c * 144 + ri * 12 + ci) * 64u + batch] = v;
                }
            }
        }
    } else if (blk < 132) {
        const int idx = blk - 96;
        const int c = idx / 12, ri = idx % 12;
        const int py = (ri < 6) ? ri : ri + 52;
        slot = c * 24 + ri; stride = 72; baseT = RC_TR; baseS = SRC_OFF;
        const int batch = tid >> 4, f4 = tid & 15;
        float4 val = ((const float4*)x)[(batch * 3 + c) * 1024 + py * 16 + f4];
        float vv[4] = {val.x, val.y, val.z, val.w};
#pragma unroll
        for (int e = 0; e < 4; ++e) {
            const int b = min(max((int)fmaf(vv[e], SCALE, 1024.f), 0), NBUCK - 1);
            atomicAdd(&sH[b], 1.f);
        }
    } else {
        const int idx = blk - 132;
        const int c = idx / 12, ci = idx % 12;
        const int pxc = (ci < 6) ? ci : ci + 52;
        slot = c * 24 + 12 + ci; stride = 72; baseT = RC_TR; baseS = SRC_OFF;
        const int batch = tid >> 4, py0 = (tid & 15) * 4;
        const float* base = x + (batch * 3 + c) * 4096 + pxc;
        float vr[4];
#pragma unroll
        for (int e = 0; e < 4; ++e) vr[e] = base[(py0 + e) * 64];
#pragma unroll
        for (int e = 0; e < 4; ++e) {
            const int b = min(max((int)fmaf(vr[e], SCALE, 1024.f), 0), NBUCK - 1);
            atomicAdd(&sH[b], 1.f);
        }
    }
    __syncthreads();

    // C/D block scan (verbatim R15, numerically validated)
    const int lane = tid & 63;
    const int wid  = tid >> 6;
    const int b0 = 2 * tid, b1 = 2 * tid + 1;
    const float c0 = sH[b0], c1 = sH[b1];
    const float d0 = (float)b0 * c0, d1 = (float)b1 * c1;
    const float cs = c0 + c1, ds = d0 + d1;
    float ic = cs, id = ds;
#pragma unroll
    for (int off = 1; off < 64; off <<= 1) {
        const float tc = __shfl_up(ic, off);
        const float td = __shfl_up(id, off);
        if (lane >= off) { ic += tc; id += td; }
    }
    if (lane == 63) { sWc[wid] = ic; sWd[wid] = id; }
    __syncthreads();
    float baseC = 0.f, baseD = 0.f, Ntot = 0.f, Dtot = 0.f;
#pragma unroll
    for (int w = 0; w < 16; ++w) {
        const float wc = sWc[w], wd = sWd[w];
        Ntot += wc; Dtot += wd;
        if (w < wid) { baseC += wc; baseD += wd; }
    }
    const float Cex = baseC + ic - cs;
    const float Dex = baseD + id - ds;
    const float T0 = WB * (Dtot + 0.5f * Ntot);

    const float Tb0 = T0 + WB * (2.f * (float)b0 * Cex - 2.f * Dex - (float)b0 * Ntot);
    const float C1 = Cex + c0, D1 = Dex + d0;
    const float Tb1 = T0 + WB * (2.f * (float)b1 * C1 - 2.f * D1 - (float)b1 * Ntot);
    tail[baseT + (unsigned)b0 * stride + slot] = Tb0;
    tail[baseT + (unsigned)b1 * stride + slot] = Tb1;
    if (tid == 1023) {
        tail[baseT + (unsigned)NBUCK * stride + slot] =
            T0 + WB * ((float)NBUCK * Ntot - 2.f * Dtot);
        tail[baseS + slot] = T0 - 6.f * Ntot;   // S = sum of snapped values
    }
}

// ---------------------------------------------------------------------------
// 2) query: 147 blocks x 512 = (q=hm*16+o) x (sub 0..15).
//    Corners: 144 iters/thread (2x finer than R15). F: sub<8 sums a float4
//    of the transposed bucket rows j, j+1 (lerp linear in tables -> sum of
//    partial lerps == lerp of summed rows); rc: sub 8..13 each handles one
//    row-inv + one col-inv slot. ~300 line-touches vs R15's ~2700 scatters.
// ---------------------------------------------------------------------------
__global__ __launch_bounds__(512) void query_kernel(
    const float* __restrict__ Kh, const float* __restrict__ Km,
    const float* __restrict__ tail, float* __restrict__ gsum)
{
    __shared__ float sC[2304];
    __shared__ float sK[32];
    __shared__ float sredA[32][16];
    __shared__ float sredL[32][16];

    const int c  = blockIdx.x / 49;
    const int t  = blockIdx.x - c * 49;
    const int dy = t / 7, dx = t - dy * 7;
    const int tid = threadIdx.x;

    for (int i = tid; i < 2304; i += 512) {
        const int cell = i >> 6, batch = i & 63;
        const int qr = cell / 6, qc = cell - qr * 6;
        const int ri = (qr < dy) ? qr : 6 + qr;
        const int ci = (qc < dx) ? qc : 6 + qc;
        sC[i] = tail[PACK + ((unsigned)c * 144 + ri * 12 + ci) * 64u + batch];
    }
    if (tid < 32)
        sK[tid] = ((tid >= 16) ? Km : Kh)[(tid & 15) * 147 + c * 49 + t];
    __syncthreads();

    const int q   = tid >> 4;           // 0..31 = hm*16+o
    const int sub = tid & 15;
    const float k = sK[q];

    float accA = 0.f, accL = 0.f;
#pragma unroll 16
    for (int step = 0; step < 144; ++step) {          // exact corners
        const float v = sC[sub + 16 * step];
        accA += fabsf(k - v);
        accL += k - v;
    }

    const float u = fmaf(k, SCALE, 1024.f);
    const int j = min(max((int)u, 0), NBUCK - 1);
    const float fr = u - (float)j;

    if (sub < 8) {
        // F: sum 4 partial-table columns (contiguous) of bucket rows j, j+1
        const v4f r0 = *(const v4f*)(tail + F_TR + (unsigned)j * 96u + c * 32 + sub * 4);
        const v4f r1 = *(const v4f*)(tail + F_TR + (unsigned)(j + 1) * 96u + c * 32 + sub * 4);
        const float s0 = r0.x + r0.y + r0.z + r0.w;
        const float s1 = r1.x + r1.y + r1.z + r1.w;
        accA += s0 + fr * (s1 - s0);
        const v4f sf = *(const v4f*)(tail + SF_OFF + c * 32 + sub * 4);
        accL -= sf.x + sf.y + sf.z + sf.w;
        if (sub == 0) accL += k * 212992.f;           // (58*58 - 36) * 64
    } else if (sub < 14) {
        const int s6 = sub - 8;                        // 0..5
        const int rinv = (s6 < dy) ? s6 : 6 + s6;
        const int cinv = (s6 < dx) ? s6 : 6 + s6;
        const int slr = c * 24 + rinv;
        const int slc = c * 24 + 12 + cinv;
        const float tr0 = tail[RC_TR + (unsigned)j * 72u + slr];
        const float tr1 = tail[RC_TR + (unsigned)(j + 1) * 72u + slr];
        const float tc0 = tail[RC_TR + (unsigned)j * 72u + slc];
        const float tc1 = tail[RC_TR + (unsigned)(j + 1) * 72u + slc];
        accA -= tr0 + fr * (tr1 - tr0);
        accA -= tc0 + fr * (tc1 - tc0);
        accL += tail[SRC_OFF + slr] + tail[SRC_OFF + slc];
    }

    sredA[q][sub] = accA;
    sredL[q][sub] = accL;
    __syncthreads();
    if (tid < 64) {
        const int idx  = tid >> 1;
        const int part = tid & 1;
        const float (*sr)[16] = part ? sredL : sredA;
        float s = 0.f;
#pragma unroll
        for (int e = 0; e < 16; ++e) s += sr[idx][e];
        atomicAdd(&gsum[part * 32 + idx], s);
    }
}

// ---------------------------------------------------------------------------
// 3) fill: fold A/L banks -> s_hit/s_miss; broadcast-fill 124 MB (roofline).
// ---------------------------------------------------------------------------
__global__ __launch_bounds__(256) void fill_kernel(
    const float* __restrict__ gsum, v4f* __restrict__ out, unsigned n4)
{
    __shared__ float sv[48];
    if (threadIdx.x < 48) {
        const int o = threadIdx.x & 15, grp = threadIdx.x >> 4;
        const float h = -0.5f * (gsum[32 + o] + gsum[o]);
        const float m =  0.5f * (gsum[16 + o] - gsum[48 + o]);
        sv[threadIdx.x] = (grp == 0) ? (h - m) : ((grp == 1) ? h : m);
    }
    __syncthreads();
    const unsigned stride = gridDim.x * blockDim.x;
    for (unsigned i = blockIdx.x * blockDim.x + threadIdx.x; i < n4; i += stride) {
        const unsigned f = i * 4u;
        const unsigned w   = f / OUT1;
        const unsigned rem = f - w * OUT1;
        const unsigned o   = (rem % OSEG) / SEG;
        const float val = sv[w * 16 + o];
        v4f pk = {val, val, val, val};
        __builtin_nontemporal_store(pk, &out[i]);
    }
}

extern "C" void kernel_launch(void* const* d_in, const int* in_sizes, int n_in,
                              void* d_out, int out_size, void* d_ws, size_t ws_size,
                              hipStream_t stream)
{
    const float* x  = (const float*)d_in[0];
    const float* Kh = (const float*)d_in[1];
    const float* Km = (const float*)d_in[2];
    float* out  = (float*)d_out;
    float* tail = out + TAIL_BASE;
    float* gsum = (float*)d_ws;    // 64 floats: [0..32) A-bank, [32..64) L-bank

    build_kernel<<<168, 1024, 0, stream>>>(x, tail, gsum);
    query_kernel<<<147, 512, 0, stream>>>(Kh, Km, tail, gsum);
    fill_kernel <<<4096, 256, 0, stream>>>(gsum, (v4f*)out, NOUT / 4u);
}